// Round 14
// baseline (262.634 us; speedup 1.0000x reference)
//
#include <hip/hip_runtime.h>
#include <hip/hip_bf16.h>

typedef __hip_bfloat16 bf16_t;
typedef __attribute__((ext_vector_type(8))) short short8;
typedef __attribute__((ext_vector_type(16))) float floatx16;

static __device__ __forceinline__ float b2f(bf16_t v) { return __bfloat162float(v); }
static __device__ __forceinline__ bf16_t f2b(float v) { return __float2bfloat16(v); }
static __device__ __forceinline__ float us2f(unsigned short u) {
    union { unsigned int i; float f; } c; c.i = ((unsigned int)u) << 16; return c.f;
}

// LDS-only barrier: does NOT drain vmcnt -> global loads issued before the
// barrier stay in flight across it (used for fused1's weight prefetch).
static __device__ __forceinline__ void barrier_lds() {
    asm volatile("s_waitcnt lgkmcnt(0)" ::: "memory");
    __builtin_amdgcn_s_barrier();
    asm volatile("" ::: "memory");
}

// Problem constants
#define NN 50000
#define EE 200000
#define GG 2048
#define BCAP 64   // in-degree cap; mean deg = 4

union U4 { uint4 v; unsigned short s[8]; };
union U2 { uint2 v; unsigned short s[4]; };

#define FZ16 {0.f,0.f,0.f,0.f,0.f,0.f,0.f,0.f,0.f,0.f,0.f,0.f,0.f,0.f,0.f,0.f}

// 32x32x16 fragment-major layout (A and B operands share it):
//   element (i, k) of an [I x K] K-major matrix lives at
//   ((i/32 * (K/16) + k/16) * 64 + ((k%16)/8)*32 + i%32) * 8 + k%8
// One wave fragment = 64 lanes x short8 = contiguous 1KB.

// ---------------------------------------------------------------------------
// Merged setup: inverted adjacency build + all 4 weight packs in ONE launch
// ---------------------------------------------------------------------------
__device__ __forceinline__ void pack_w1_body(const float* __restrict__ Wa,
                                             const float* __restrict__ Wb,
                                             bf16_t* __restrict__ out,
                                             int K1, int K2, int idx) {
    int K = K1 + K2;
    int KT16 = K >> 4;
    int e = idx & 7;
    int l = (idx >> 3) & 63;
    int tile = idx >> 9;
    int kt = tile % KT16, t = tile / KT16;
    int c = t * 32 + (l & 31);
    int k = kt * 16 + (l >> 5) * 8 + e;
    float v = 0.f;
    if (c < 1000) v = (k < K1) ? Wa[c * K1 + k] : Wb[c * K2 + (k - K1)];
    out[idx] = f2b(v);
}
__device__ __forceinline__ void pack_w2_body(const float* __restrict__ Wa,
                                             const float* __restrict__ Wb,
                                             bf16_t* __restrict__ out,
                                             int OH, int idx) {
    int e = idx & 7;
    int l = (idx >> 3) & 63;
    int tile = idx >> 9;
    int kt2 = tile & 63, o = tile >> 6;   // K=1024 -> 64 k-tiles
    int c = o * 32 + (l & 31);
    int k = kt2 * 16 + (l >> 5) * 8 + e;
    float v = 0.f;
    if (k < 1000) v = (c < OH) ? Wa[c * 1000 + k] : Wb[(c - OH) * 1000 + k];
    out[idx] = f2b(v);
}

#define NB_BUILD 782   // (EE+255)/256
#define NB_P1 512      // 131072/256
#define NB_P2 1024     // 262144/256
#define NB_P3 1024
#define NB_P4 512

__global__ void setup_all(const int* __restrict__ ei, int* __restrict__ cnt,
                          int* __restrict__ bkt,
                          const float* __restrict__ W1_rel, const float* __restrict__ W1_root,
                          const float* __restrict__ W2_rel, const float* __restrict__ W2_root,
                          const float* __restrict__ W3_rel, const float* __restrict__ W3_root,
                          const float* __restrict__ W4_rel, const float* __restrict__ W4_root,
                          bf16_t* __restrict__ W1f, bf16_t* __restrict__ W2f,
                          bf16_t* __restrict__ W3f, bf16_t* __restrict__ W4f) {
    int b = blockIdx.x;
    int tid = threadIdx.x;
    if (b < NB_BUILD) {
        int e = b * 256 + tid;
        if (e < EE) {
            int s = ei[e];
            int d = ei[EE + e];
            int pos = atomicAdd(&cnt[d], 1);
            if (pos < BCAP) bkt[d * BCAP + pos] = s;
        }
    } else if (b < NB_BUILD + NB_P1) {
        pack_w1_body(W1_rel, W1_root, W1f, 64, 64, (b - NB_BUILD) * 256 + tid);
    } else if (b < NB_BUILD + NB_P1 + NB_P2) {
        pack_w2_body(W2_rel, W2_root, W2f, 128, (b - NB_BUILD - NB_P1) * 256 + tid);
    } else if (b < NB_BUILD + NB_P1 + NB_P2 + NB_P3) {
        pack_w1_body(W3_rel, W3_root, W3f, 128, 128, (b - NB_BUILD - NB_P1 - NB_P2) * 256 + tid);
    } else {
        pack_w2_body(W4_rel, W4_root, W4f, 64, (b - NB_BUILD - NB_P1 - NB_P2 - NB_P3) * 256 + tid);
    }
}

// ---------------------------------------------------------------------------
// Per-graph fused gather+relu+mean-pool (one block = one graph; batch sorted).
// v19: 512 threads = 32 node-slots x 16 col-groups. Graphs avg ~24.4 nodes;
// at 16 slots most blocks needed 2 serial node-rounds; at 32 slots nearly
// all finish in 1 (halves the dependent-gather critical path).
// Pool partials reduced in LDS (r6 lesson: NO cross-XCD f32 atomics).
// ---------------------------------------------------------------------------
__global__ void gather_relu_pool(const bf16_t* __restrict__ y2, const bf16_t* __restrict__ init,
                                 const int* __restrict__ cnt, const int* __restrict__ bkt,
                                 const int* __restrict__ batch,
                                 bf16_t* __restrict__ h2, float* __restrict__ enc, int Nn) {
    int g = blockIdx.x;
    __shared__ int s_lo, s_hi;
    __shared__ float red[32][128];   // 16KB partials
    if (threadIdx.x == 0) {
        int lo = 0, hi = Nn;
        while (lo < hi) { int mid = (lo + hi) >> 1; if (batch[mid] < g) lo = mid + 1; else hi = mid; }
        s_lo = lo;
        hi = Nn;
        while (lo < hi) { int mid = (lo + hi) >> 1; if (batch[mid] < g + 1) lo = mid + 1; else hi = mid; }
        s_hi = lo;
    }
    __syncthreads();
    const int lo = s_lo, hi = s_hi;
    const int slot = threadIdx.x >> 4;      // 0..31 node slot
    const int j = (threadIdx.x & 15) * 8;   // col group
    float psum[8] = {0.f,0.f,0.f,0.f,0.f,0.f,0.f,0.f};
    for (int n = lo + slot; n < hi; n += 32) {
        int c = cnt[n]; if (c > BCAP) c = BCAP;
        const int* bp = bkt + n * BCAP;
        U4 u; u.v = *(const uint4*)(init + (size_t)n * 128 + j);
        float s[8];
        #pragma unroll
        for (int k = 0; k < 8; ++k) s[k] = us2f(u.s[k]);
        int i = 0;
        for (; i + 4 <= c; i += 4) {
            int s0 = bp[i], s1 = bp[i + 1], s2 = bp[i + 2], s3 = bp[i + 3];
            U4 w0, w1, w2, w3;
            w0.v = *(const uint4*)(y2 + (size_t)s0 * 128 + j);
            w1.v = *(const uint4*)(y2 + (size_t)s1 * 128 + j);
            w2.v = *(const uint4*)(y2 + (size_t)s2 * 128 + j);
            w3.v = *(const uint4*)(y2 + (size_t)s3 * 128 + j);
            #pragma unroll
            for (int k = 0; k < 8; ++k)
                s[k] += (us2f(w0.s[k]) + us2f(w1.s[k])) + (us2f(w2.s[k]) + us2f(w3.s[k]));
        }
        for (; i < c; ++i) {
            U4 w; w.v = *(const uint4*)(y2 + (size_t)bp[i] * 128 + j);
            #pragma unroll
            for (int k = 0; k < 8; ++k) s[k] += us2f(w.s[k]);
        }
        alignas(16) bf16_t ob[8];
        #pragma unroll
        for (int k = 0; k < 8; ++k) {
            s[k] = fmaxf(s[k], 0.f);
            psum[k] += s[k];
            ob[k] = f2b(s[k]);
        }
        *(uint4*)(h2 + (size_t)n * 128 + j) = *(const uint4*)ob;
    }
    #pragma unroll
    for (int k = 0; k < 8; ++k) red[slot][j + k] = psum[k];
    __syncthreads();
    if (threadIdx.x < 128) {
        int c = threadIdx.x;
        float tot = 0.f;
        #pragma unroll
        for (int r = 0; r < 32; ++r) tot += red[r][c];
        float n = (float)((hi - lo) > 0 ? (hi - lo) : 1);
        enc[(size_t)g * 128 + c] = tot / n;
    }
}

// outF[n] += sum nbr y4   (y4 bf16 [N,64]; outF f32 in-place on d_out)
__global__ void gather_add_b16_64(const bf16_t* __restrict__ y4, const int* __restrict__ cnt,
                                  const int* __restrict__ bkt, float* __restrict__ outF) {
    int t = blockIdx.x * 256 + threadIdx.x;
    int n = t >> 4;
    if (n >= NN) return;
    int j = (t & 15) * 4;
    int c = cnt[n]; if (c > BCAP) c = BCAP;
    const int* bp = bkt + n * BCAP;
    float4 sum = *(const float4*)(outF + n * 64 + j);
    int i = 0;
    for (; i + 4 <= c; i += 4) {
        int s0 = bp[i], s1 = bp[i + 1], s2 = bp[i + 2], s3 = bp[i + 3];
        U2 w0, w1, w2, w3;
        w0.v = *(const uint2*)(y4 + (size_t)s0 * 64 + j);
        w1.v = *(const uint2*)(y4 + (size_t)s1 * 64 + j);
        w2.v = *(const uint2*)(y4 + (size_t)s2 * 64 + j);
        w3.v = *(const uint2*)(y4 + (size_t)s3 * 64 + j);
        sum.x += (us2f(w0.s[0]) + us2f(w1.s[0])) + (us2f(w2.s[0]) + us2f(w3.s[0]));
        sum.y += (us2f(w0.s[1]) + us2f(w1.s[1])) + (us2f(w2.s[1]) + us2f(w3.s[1]));
        sum.z += (us2f(w0.s[2]) + us2f(w1.s[2])) + (us2f(w2.s[2]) + us2f(w3.s[2]));
        sum.w += (us2f(w0.s[3]) + us2f(w1.s[3])) + (us2f(w2.s[3]) + us2f(w3.s[3]));
    }
    for (; i < c; ++i) {
        U2 w; w.v = *(const uint2*)(y4 + (size_t)bp[i] * 64 + j);
        sum.x += us2f(w.s[0]); sum.y += us2f(w.s[1]);
        sum.z += us2f(w.s[2]); sum.w += us2f(w.s[3]);
    }
    *(float4*)(outF + n * 64 + j) = sum;
}

// ---------------------------------------------------------------------------
// Fused gather + two-GEMM v18 (unchanged from r13 — best measured config):
//   K=128 (fused1, NOUT=256): PD=4 cross-phase w1 prefetch (16 VGPRs live
//     across barriers, cheap) + 8-deep stage-2 with W2 dedup.
//   K=256 (fused2, NOUT=128): v16 path — 8-deep batches, no cross-phase
//     prefetch (PD=8 prefetch regressed: 32 VGPRs live across H-write).
//   Block = 64 nodes (2 node-tiles of 32), 512 threads = 8 waves.
// Outputs: outcol < NOUT/2 -> yout (bf16 if YBF16), else initout (+bias2).
// ---------------------------------------------------------------------------
template <int K, int NOUT, int F32OUT, int YBF16, int SRCF32>
__global__ __launch_bounds__(512, 4) void fused18(
    const void* __restrict__ src, const int* __restrict__ cnt,
    const int* __restrict__ bkt,
    const bf16_t* __restrict__ W1f, const float* __restrict__ bias1,
    const bf16_t* __restrict__ W2f, const float* __restrict__ bias2,
    void* __restrict__ yout, void* __restrict__ initout)
{
    constexpr int KT16 = K / 16;      // A k-tiles (16-deep): 8 or 16
    constexpr bool PREF = (K == 128); // cross-phase prefetch only when PD=4
    constexpr int PD   = KT16 / 2;    // w1 batch depth (4 or 8); 2 rounds
    constexpr int OT32 = NOUT / 32;   // out 32-col tiles (8 or 4)
    constexpr int OCT2 = OT32 / 4;    // out tiles per wave, old mapping (2 or 1)
    constexpr int NACC = (NOUT == 256) ? 2 : OCT2;
    constexpr int OH   = NOUT / 2;
    constexpr int SW   = K / 2;       // source row width (64 f32 / 128 bf16)
    constexpr int HALF = K / 16;      // 8-col groups per half (8 or 16)
    constexpr int STR  = F32OUT ? (NOUT + 4) : (NOUT + 8);
    __shared__ float b1sl[1024];
    __shared__ float b2sl[128];
    __shared__ __align__(16) char smem[(size_t)64 * K * 2 + 64 * 256 * 2];
    bf16_t* Asl = (bf16_t*)smem;                        // frag-major A tile [64*K]
    bf16_t* Hsl = (bf16_t*)(smem + (size_t)64 * K * 2); // frag-major H chunk [64*256]

    const int tid  = threadIdx.x;
    const int lane = tid & 63;
    const int wn   = tid >> 6;        // 0..7
    const int l31  = lane & 31;
    const int hi   = lane >> 5;
    const int og   = wn >> 1;         // old stage-2 out-col group
    const int wr   = wn & 1;          // old stage-2 node-tile
    const int bm0  = blockIdx.x * 64;

    for (int i = tid; i < 1024; i += 512) b1sl[i] = (i < 1000) ? bias1[i] : 0.f;
    if (tid < OH) b2sl[tid] = bias2[tid];

    // ---- prologue: gather + own-copy directly into Asl (frag-major)
    #pragma unroll
    for (int it = 0; it < (2 * 64 * HALF) / 512; ++it) {
        int task = it * 512 + tid;
        const bool own = task >= 64 * HALF;
        int t2 = own ? task - 64 * HALF : task;
        int i = t2 / HALF, s = t2 - (t2 / HALF) * HALF;
        int n = bm0 + i;
        int j = s * 8;
        float sum[8] = {0.f, 0.f, 0.f, 0.f, 0.f, 0.f, 0.f, 0.f};
        if (n < NN) {
            if (!own) {
                int c = cnt[n]; if (c > BCAP) c = BCAP;
                const int* bp = bkt + n * BCAP;
                int e = 0;
                for (; e + 4 <= c; e += 4) {
                    int s0 = bp[e], s1 = bp[e + 1], s2 = bp[e + 2], s3 = bp[e + 3];
                    if (SRCF32) {
                        const float* r0 = (const float*)src + (size_t)s0 * SW + j;
                        const float* r1 = (const float*)src + (size_t)s1 * SW + j;
                        const float* r2 = (const float*)src + (size_t)s2 * SW + j;
                        const float* r3 = (const float*)src + (size_t)s3 * SW + j;
                        float4 a0 = *(const float4*)r0, b0 = *(const float4*)(r0 + 4);
                        float4 a1 = *(const float4*)r1, b1 = *(const float4*)(r1 + 4);
                        float4 a2 = *(const float4*)r2, b2 = *(const float4*)(r2 + 4);
                        float4 a3 = *(const float4*)r3, b3 = *(const float4*)(r3 + 4);
                        sum[0] += (a0.x + a1.x) + (a2.x + a3.x);
                        sum[1] += (a0.y + a1.y) + (a2.y + a3.y);
                        sum[2] += (a0.z + a1.z) + (a2.z + a3.z);
                        sum[3] += (a0.w + a1.w) + (a2.w + a3.w);
                        sum[4] += (b0.x + b1.x) + (b2.x + b3.x);
                        sum[5] += (b0.y + b1.y) + (b2.y + b3.y);
                        sum[6] += (b0.z + b1.z) + (b2.z + b3.z);
                        sum[7] += (b0.w + b1.w) + (b2.w + b3.w);
                    } else {
                        U4 w0, w1, w2, w3;
                        w0.v = *(const uint4*)((const bf16_t*)src + (size_t)s0 * SW + j);
                        w1.v = *(const uint4*)((const bf16_t*)src + (size_t)s1 * SW + j);
                        w2.v = *(const uint4*)((const bf16_t*)src + (size_t)s2 * SW + j);
                        w3.v = *(const uint4*)((const bf16_t*)src + (size_t)s3 * SW + j);
                        #pragma unroll
                        for (int k = 0; k < 8; ++k)
                            sum[k] += (us2f(w0.s[k]) + us2f(w1.s[k])) + (us2f(w2.s[k]) + us2f(w3.s[k]));
                    }
                }
                for (; e < c; ++e) {
                    int sn = bp[e];
                    if (SRCF32) {
                        const float* r = (const float*)src + (size_t)sn * SW + j;
                        float4 a = *(const float4*)r;
                        float4 b = *(const float4*)(r + 4);
                        sum[0] += a.x; sum[1] += a.y; sum[2] += a.z; sum[3] += a.w;
                        sum[4] += b.x; sum[5] += b.y; sum[6] += b.z; sum[7] += b.w;
                    } else {
                        U4 w; w.v = *(const uint4*)((const bf16_t*)src + (size_t)sn * SW + j);
                        #pragma unroll
                        for (int k = 0; k < 8; ++k) sum[k] += us2f(w.s[k]);
                    }
                }
            } else {
                if (SRCF32) {
                    const float* r = (const float*)src + (size_t)n * SW + j;
                    float4 a = *(const float4*)r;
                    float4 b = *(const float4*)(r + 4);
                    sum[0] = a.x; sum[1] = a.y; sum[2] = a.z; sum[3] = a.w;
                    sum[4] = b.x; sum[5] = b.y; sum[6] = b.z; sum[7] = b.w;
                } else {
                    U4 w; w.v = *(const uint4*)((const bf16_t*)src + (size_t)n * SW + j);
                    #pragma unroll
                    for (int k = 0; k < 8; ++k) sum[k] = us2f(w.s[k]);
                }
            }
        }
        int cc = (own ? K / 2 : 0) + j;           // column in A's K-space
        int off = (((i >> 5) * KT16 + (cc >> 4)) * 64 + ((cc >> 3) & 1) * 32 + (i & 31)) * 8;
        alignas(16) bf16_t ob[8];
        #pragma unroll
        for (int k = 0; k < 8; ++k) ob[k] = f2b(sum[k]);
        *(uint4*)(&Asl[off]) = *(const uint4*)ob;
    }

    floatx16 acc2[NACC];
    #pragma unroll
    for (int oo = 0; oo < NACC; ++oo) acc2[oo] = (floatx16)FZ16;

    // (PREF only) prefetch chunk-0's first w1 batch BEFORE the barrier
    short8 w1pre[PD];
    if (PREF) {
        const bf16_t* w1p0 = W1f + (((size_t)(0 * 8 + wn) * KT16) * 64 + lane) * 8;
        #pragma unroll
        for (int u = 0; u < PD; ++u)
            w1pre[u] = *(const short8*)(w1p0 + (size_t)u * 512);
    }

    barrier_lds();   // Asl + biases ready

    for (int ci = 0; ci < 4; ++ci) {
        // ---- stage 1
        floatx16 acc1[2];
        acc1[0] = (floatx16)FZ16;
        acc1[1] = (floatx16)FZ16;

        const bf16_t* w1p = W1f + (((size_t)(ci * 8 + wn) * KT16) * 64 + lane) * 8;
        if (PREF) {
            // batch 0 from w1pre (in flight across barrier)
            __builtin_amdgcn_s_setprio(1);
            #pragma unroll
            for (int u = 0; u < PD; ++u) {
                short8 av0 = *(const short8*)&Asl[((0 * KT16 + u) * 64 + lane) * 8];
                acc1[0] = __builtin_amdgcn_mfma_f32_32x32x16_bf16(w1pre[u], av0, acc1[0], 0, 0, 0);
                short8 av1 = *(const short8*)&Asl[((1 * KT16 + u) * 64 + lane) * 8];
                acc1[1] = __builtin_amdgcn_mfma_f32_32x32x16_bf16(w1pre[u], av1, acc1[1], 0, 0, 0);
            }
            __builtin_amdgcn_s_setprio(0);
            short8 w1v[PD];
            #pragma unroll
            for (int u = 0; u < PD; ++u)
                w1v[u] = *(const short8*)(w1p + (size_t)(PD + u) * 512);
            __builtin_amdgcn_s_setprio(1);
            #pragma unroll
            for (int u = 0; u < PD; ++u) {
                int kk = PD + u;
                short8 av0 = *(const short8*)&Asl[((0 * KT16 + kk) * 64 + lane) * 8];
                acc1[0] = __builtin_amdgcn_mfma_f32_32x32x16_bf16(w1v[u], av0, acc1[0], 0, 0, 0);
                short8 av1 = *(const short8*)&Asl[((1 * KT16 + kk) * 64 + lane) * 8];
                acc1[1] = __builtin_amdgcn_mfma_f32_32x32x16_bf16(w1v[u], av1, acc1[1], 0, 0, 0);
            }
            __builtin_amdgcn_s_setprio(0);
        } else {
            // 8-deep batches, 2 rounds, no cross-phase prefetch
            #pragma unroll 1
            for (int kh = 0; kh < KT16 / 8; ++kh) {
                short8 w1v[8];
                #pragma unroll
                for (int u = 0; u < 8; ++u)
                    w1v[u] = *(const short8*)(w1p + (size_t)(kh * 8 + u) * 512);
                __builtin_amdgcn_s_setprio(1);
                #pragma unroll
                for (int u = 0; u < 8; ++u) {
                    int kk = kh * 8 + u;
                    short8 av0 = *(const short8*)&Asl[((0 * KT16 + kk) * 64 + lane) * 8];
                    acc1[0] = __builtin_amdgcn_mfma_f32_32x32x16_bf16(w1v[u], av0, acc1[0], 0, 0, 0);
                    short8 av1 = *(const short8*)&Asl[((1 * KT16 + kk) * 64 + lane) * 8];
                    acc1[1] = __builtin_amdgcn_mfma_f32_32x32x16_bf16(w1v[u], av1, acc1[1], 0, 0, 0);
                }
                __builtin_amdgcn_s_setprio(0);
            }
        }

        barrier_lds();   // previous chunk's stage-2 readers done with Hsl

        // bias+relu -> frag-major H; C/D: node=l31, hcol32=(r&3)+8*(r>>2)+4*hi
        #pragma unroll
        for (int nt2 = 0; nt2 < 2; ++nt2) {
            #pragma unroll
            for (int g = 0; g < 4; ++g) {
                float4 bv = *(const float4*)&b1sl[ci * 256 + wn * 32 + 8 * g + 4 * hi];
                const float* bvp = (const float*)&bv;
                alignas(8) bf16_t hb[4];
                #pragma unroll
                for (int e = 0; e < 4; ++e)
                    hb[e] = f2b(fmaxf(acc1[nt2][4 * g + e] + bvp[e], 0.f));
                int off = ((nt2 * 16 + wn * 2 + (g >> 1)) * 64 + (g & 1) * 32 + l31) * 8 + 4 * hi;
                *(uint2*)&Hsl[off] = *(const uint2*)hb;
            }
        }

        barrier_lds();   // H chunk visible

        // ---- stage 2
        if (NOUT == 256) {
            // dedup mapping + cross-phase w1 prefetch (PD=4, cheap)
            const int cin = (ci < 3) ? ci + 1 : 0;
            const bf16_t* w1pn = W1f + (((size_t)(cin * 8 + wn) * KT16) * 64 + lane) * 8;
            const bf16_t* w2p = W2f + (((size_t)wn * 64 + ci * 16) * 64 + lane) * 8;
            short8 w2v[8];
            // round 0: ks 0..7
            #pragma unroll
            for (int u = 0; u < 8; ++u)
                w2v[u] = *(const short8*)(w2p + (size_t)u * 512);
            __builtin_amdgcn_s_setprio(1);
            #pragma unroll
            for (int u = 0; u < 8; ++u) {
                short8 hf0 = *(const short8*)&Hsl[((0 * 16 + u) * 64 + lane) * 8];
                acc2[0] = __builtin_amdgcn_mfma_f32_32x32x16_bf16(w2v[u], hf0, acc2[0], 0, 0, 0);
                short8 hf1 = *(const short8*)&Hsl[((1 * 16 + u) * 64 + lane) * 8];
                acc2[1] = __builtin_amdgcn_mfma_f32_32x32x16_bf16(w2v[u], hf1, acc2[1], 0, 0, 0);
            }
            __builtin_amdgcn_s_setprio(0);
            // round 1: ks 8..15 + w1 prefetch for cin
            #pragma unroll
            for (int u = 0; u < 8; ++u)
                w2v[u] = *(const short8*)(w2p + (size_t)(8 + u) * 512);
            #pragma unroll
            for (int u = 0; u < PD; ++u)
                w1pre[u] = *(const short8*)(w1pn + (size_t)u * 512);
            __builtin_amdgcn_s_setprio(1);
            #pragma unroll
            for (int u = 0; u < 8; ++u) {
                int ks = 8 + u;
                short8 hf0 = *(const short8*)&Hsl[((0 * 16 + ks) * 64 + lane) * 8];
                acc2[0] = __builtin_amdgcn_mfma_f32_32x32x16_bf16(w2v[u], hf0, acc2[0], 0, 0, 0);
                short8 hf1 = *(const short8*)&Hsl[((1 * 16 + ks) * 64 + lane) * 8];
                acc2[1] = __builtin_amdgcn_mfma_f32_32x32x16_bf16(w2v[u], hf1, acc2[1], 0, 0, 0);
            }
            __builtin_amdgcn_s_setprio(0);
        } else {
            // wave (og, wr): 1 out-tile x node-tile wr; 8-deep
            const bf16_t* w2p = W2f + ((((size_t)og) * 64 + ci * 16) * 64 + lane) * 8;
            #pragma unroll 1
            for (int kg = 0; kg < 2; ++kg) {
                short8 w2v[8];
                #pragma unroll
                for (int u = 0; u < 8; ++u)
                    w2v[u] = *(const short8*)(w2p + (size_t)(kg * 8 + u) * 512);
                __builtin_amdgcn_s_setprio(1);
                #pragma unroll
                for (int u = 0; u < 8; ++u) {
                    int ks = kg * 8 + u;
                    short8 hf = *(const short8*)&Hsl[((wr * 16 + ks) * 64 + lane) * 8];
                    acc2[0] = __builtin_amdgcn_mfma_f32_32x32x16_bf16(w2v[u], hf, acc2[0], 0, 0, 0);
                }
                __builtin_amdgcn_s_setprio(0);
            }
        }
    }

    // ---- epilogue: stage acc2(+bias) into LDS [node][outcol] (padded),
    //      then copy full rows out with coalesced line-aligned stores.
    barrier_lds();   // everyone done reading Hsl/Asl
    if (NOUT == 256) {
        bf16_t* st = (bf16_t*)smem;
        #pragma unroll
        for (int nt2 = 0; nt2 < 2; ++nt2) {
            const int r = nt2 * 32 + l31;
            #pragma unroll
            for (int g = 0; g < 4; ++g) {
                int oc = wn * 32 + 8 * g + 4 * hi;
                const bool isInit = (oc >= OH);
                int col = isInit ? oc - OH : oc;
                float4 bv = isInit ? *(const float4*)&b2sl[col]
                                   : make_float4(0.f, 0.f, 0.f, 0.f);
                const float* bvp = (const float*)&bv;
                alignas(8) bf16_t ob[4];
                #pragma unroll
                for (int e = 0; e < 4; ++e) ob[e] = f2b(acc2[nt2][4 * g + e] + bvp[e]);
                *(uint2*)&st[r * STR + oc] = *(const uint2*)ob;
            }
        }
    } else {
        const int r = wr * 32 + l31;   // node row within block
        float* st = (float*)smem;      // f32 staging (F32OUT=1 for NOUT=128)
        #pragma unroll
        for (int oo = 0; oo < OCT2; ++oo) {
            int o = og * OCT2 + oo;
            #pragma unroll
            for (int g = 0; g < 4; ++g) {
                int oc = o * 32 + 8 * g + 4 * hi;
                const bool isInit = (oc >= OH);
                int col = isInit ? oc - OH : oc;
                float4 bv = isInit ? *(const float4*)&b2sl[col]
                                   : make_float4(0.f, 0.f, 0.f, 0.f);
                const float* bvp = (const float*)&bv;
                float v[4];
                #pragma unroll
                for (int e = 0; e < 4; ++e) v[e] = acc2[oo][4 * g + e] + bvp[e];
                *(float4*)&st[r * STR + oc] = make_float4(v[0], v[1], v[2], v[3]);
            }
        }
    }
    barrier_lds();   // staging written
    if (NOUT == 256) {
        constexpr int CH = NOUT / 8;
        constexpr int CHH = CH / 2;
        const bf16_t* st = (const bf16_t*)smem;
        for (int t = tid; t < 64 * CH; t += 512) {
            int nd = t / CH, c = t - (t / CH) * CH;
            int node = bm0 + nd;
            if (node >= NN) continue;
            const bool isInit = (c >= CHH);
            int ch = isInit ? c - CHH : c;
            uint4 v = *(const uint4*)&st[nd * STR + c * 8];
            bf16_t* dst = isInit ? (bf16_t*)initout : (bf16_t*)yout;
            *(uint4*)(dst + (size_t)node * OH + ch * 8) = v;
        }
    } else {
        const float* st = (const float*)smem;
        for (int t = tid; t < 64 * (OH / 4); t += 512) {
            int nd = t / (OH / 4), c = t - (t / (OH / 4)) * (OH / 4);
            int node = bm0 + nd;
            if (node >= NN) continue;
            float4 v = *(const float4*)&st[nd * STR + OH + c * 4];
            *(float4*)((float*)initout + (size_t)node * OH + c * 4) = v;
        }
        if (YBF16) {
            for (int t = tid; t < 64 * (OH / 8); t += 512) {
                int nd = t / (OH / 8), c = t - (t / (OH / 8)) * (OH / 8);
                int node = bm0 + nd;
                if (node >= NN) continue;
                float4 a = *(const float4*)&st[nd * STR + c * 8];
                float4 b = *(const float4*)&st[nd * STR + c * 8 + 4];
                alignas(16) bf16_t ob[8];
                ob[0] = f2b(a.x); ob[1] = f2b(a.y); ob[2] = f2b(a.z); ob[3] = f2b(a.w);
                ob[4] = f2b(b.x); ob[5] = f2b(b.y); ob[6] = f2b(b.z); ob[7] = f2b(b.w);
                *(uint4*)((bf16_t*)yout + (size_t)node * OH + c * 8) = *(const uint4*)ob;
            }
        } else {
            for (int t = tid; t < 64 * (OH / 4); t += 512) {
                int nd = t / (OH / 4), c = t - (t / (OH / 4)) * (OH / 4);
                int node = bm0 + nd;
                if (node >= NN) continue;
                float4 v = *(const float4*)&st[nd * STR + c * 4];
                *(float4*)((float*)yout + (size_t)node * OH + c * 4) = v;
            }
        }
    }
}

// ---------------------------------------------------------------------------
// Launch
// ---------------------------------------------------------------------------
extern "C" void kernel_launch(void* const* d_in, const int* in_sizes, int n_in,
                              void* d_out, int out_size, void* d_ws, size_t ws_size,
                              hipStream_t stream) {
    const float* x       = (const float*)d_in[0];
    const int*   ei      = (const int*)d_in[1];
    const int*   batch   = (const int*)d_in[2];
    const float* W1_rel  = (const float*)d_in[3];
    const float* b1      = (const float*)d_in[4];
    const float* W1_root = (const float*)d_in[5];
    const float* W2_rel  = (const float*)d_in[6];
    const float* b2      = (const float*)d_in[7];
    const float* W2_root = (const float*)d_in[8];
    const float* W3_rel  = (const float*)d_in[9];
    const float* b3      = (const float*)d_in[10];
    const float* W3_root = (const float*)d_in[11];
    const float* W4_rel  = (const float*)d_in[12];
    const float* b4      = (const float*)d_in[13];
    const float* W4_root = (const float*)d_in[14];

    float* outF = (float*)d_out;            // [N,64] then [G,128]
    float* enc  = outF + NN * 64;

    char* ws = (char*)d_ws;                         // ~66 MB
    bf16_t* y2buf  = (bf16_t*)(ws + 0);             // [N,128] bf16
    bf16_t* h2init = (bf16_t*)(ws + 12800000ULL);   // [N,128] bf16
    bf16_t* h2buf  = (bf16_t*)(ws + 25600000ULL);   // [N,128] bf16
    bf16_t* y4buf  = (bf16_t*)(ws + 38400000ULL);   // [N,64] bf16
    int*    cnt    = (int*)(ws + 51200000ULL);      // [N]
    int*    bkt    = (int*)(ws + 51400064ULL);      // [N*64]
    bf16_t* W1f    = (bf16_t*)(ws + 64200064ULL);   // 1024x128 frag-major
    bf16_t* W2f    = (bf16_t*)(ws + 64462208ULL);   // 256x1024 frag-major
    bf16_t* W3f    = (bf16_t*)(ws + 64986496ULL);   // 1024x256 frag-major
    bf16_t* W4f    = (bf16_t*)(ws + 65510784ULL);   // 128x1024 frag-major

    const int RB64 = (NN + 63) / 64;  // 782

    // ---- adjacency + all weight packs in one launch
    hipMemsetAsync(cnt, 0, NN * sizeof(int), stream);
    setup_all<<<NB_BUILD + NB_P1 + NB_P2 + NB_P3 + NB_P4, 256, 0, stream>>>(
        ei, cnt, bkt, W1_rel, W1_root, W2_rel, W2_root,
        W3_rel, W3_root, W4_rel, W4_root, W1f, W2f, W3f, W4f);

    // ---- L1+L2 fused: A=[gather(x)|x]; h1 on-chip;
    //      y2 = h1@W2_rel^T (bf16), h2init = h1@W2_root^T + b2 (bf16)
    fused18<128, 256, 0, 0, 1><<<RB64, 512, 0, stream>>>(x, cnt, bkt, W1f, b1, W2f, b2, y2buf, h2init);

    // ---- h2 = relu(h2init + gather(y2)); encoded = mean-pool(h2), fused
    gather_relu_pool<<<GG, 512, 0, stream>>>(y2buf, h2init, cnt, bkt, batch, h2buf, enc, NN);

    // ---- L3+L4 fused: A=[gather(h2)|h2]; h3 on-chip;
    //      y4 = h3@W4_rel^T (bf16), outF = h3@W4_root^T + b4 (f32, direct)
    fused18<256, 128, 1, 1, 0><<<RB64, 512, 0, stream>>>(h2buf, cnt, bkt, W3f, b3, W4f, b4, y4buf, outF);

    // ---- out = outF + gather(y4)   (y4 bf16 halves neighbor-read traffic)
    gather_add_b16_64<<<(NN * 16 + 255) / 256, 256, 0, stream>>>(y4buf, cnt, bkt, outF);
}

// Round 15
// 259.412 us; speedup vs baseline: 1.0124x; 1.0124x over previous
//
#include <hip/hip_runtime.h>
#include <hip/hip_bf16.h>

typedef __hip_bfloat16 bf16_t;
typedef __attribute__((ext_vector_type(8))) short short8;
typedef __attribute__((ext_vector_type(16))) float floatx16;

static __device__ __forceinline__ float b2f(bf16_t v) { return __bfloat162float(v); }
static __device__ __forceinline__ bf16_t f2b(float v) { return __float2bfloat16(v); }
static __device__ __forceinline__ float us2f(unsigned short u) {
    union { unsigned int i; float f; } c; c.i = ((unsigned int)u) << 16; return c.f;
}

// LDS-only barrier: does NOT drain vmcnt -> global loads issued before the
// barrier stay in flight across it (used for fused1's weight prefetch).
static __device__ __forceinline__ void barrier_lds() {
    asm volatile("s_waitcnt lgkmcnt(0)" ::: "memory");
    __builtin_amdgcn_s_barrier();
    asm volatile("" ::: "memory");
}

// Problem constants
#define NN 50000
#define EE 200000
#define GG 2048
#define BCAP 64   // in-degree cap; mean deg = 4

union U4 { uint4 v; unsigned short s[8]; };
union U2 { uint2 v; unsigned short s[4]; };

#define FZ16 {0.f,0.f,0.f,0.f,0.f,0.f,0.f,0.f,0.f,0.f,0.f,0.f,0.f,0.f,0.f,0.f}

// 32x32x16 fragment-major layout (A and B operands share it):
//   element (i, k) of an [I x K] K-major matrix lives at
//   ((i/32 * (K/16) + k/16) * 64 + ((k%16)/8)*32 + i%32) * 8 + k%8
// One wave fragment = 64 lanes x short8 = contiguous 1KB.

// ---------------------------------------------------------------------------
// Merged setup: inverted adjacency build + all 4 weight packs in ONE launch
// ---------------------------------------------------------------------------
__device__ __forceinline__ void pack_w1_body(const float* __restrict__ Wa,
                                             const float* __restrict__ Wb,
                                             bf16_t* __restrict__ out,
                                             int K1, int K2, int idx) {
    int K = K1 + K2;
    int KT16 = K >> 4;
    int e = idx & 7;
    int l = (idx >> 3) & 63;
    int tile = idx >> 9;
    int kt = tile % KT16, t = tile / KT16;
    int c = t * 32 + (l & 31);
    int k = kt * 16 + (l >> 5) * 8 + e;
    float v = 0.f;
    if (c < 1000) v = (k < K1) ? Wa[c * K1 + k] : Wb[c * K2 + (k - K1)];
    out[idx] = f2b(v);
}
__device__ __forceinline__ void pack_w2_body(const float* __restrict__ Wa,
                                             const float* __restrict__ Wb,
                                             bf16_t* __restrict__ out,
                                             int OH, int idx) {
    int e = idx & 7;
    int l = (idx >> 3) & 63;
    int tile = idx >> 9;
    int kt2 = tile & 63, o = tile >> 6;   // K=1024 -> 64 k-tiles
    int c = o * 32 + (l & 31);
    int k = kt2 * 16 + (l >> 5) * 8 + e;
    float v = 0.f;
    if (k < 1000) v = (c < OH) ? Wa[c * 1000 + k] : Wb[(c - OH) * 1000 + k];
    out[idx] = f2b(v);
}

#define NB_BUILD 782   // (EE+255)/256
#define NB_P1 512      // 131072/256
#define NB_P2 1024     // 262144/256
#define NB_P3 1024
#define NB_P4 512

__global__ void setup_all(const int* __restrict__ ei, int* __restrict__ cnt,
                          int* __restrict__ bkt,
                          const float* __restrict__ W1_rel, const float* __restrict__ W1_root,
                          const float* __restrict__ W2_rel, const float* __restrict__ W2_root,
                          const float* __restrict__ W3_rel, const float* __restrict__ W3_root,
                          const float* __restrict__ W4_rel, const float* __restrict__ W4_root,
                          bf16_t* __restrict__ W1f, bf16_t* __restrict__ W2f,
                          bf16_t* __restrict__ W3f, bf16_t* __restrict__ W4f) {
    int b = blockIdx.x;
    int tid = threadIdx.x;
    if (b < NB_BUILD) {
        int e = b * 256 + tid;
        if (e < EE) {
            int s = ei[e];
            int d = ei[EE + e];
            int pos = atomicAdd(&cnt[d], 1);
            if (pos < BCAP) bkt[d * BCAP + pos] = s;
        }
    } else if (b < NB_BUILD + NB_P1) {
        pack_w1_body(W1_rel, W1_root, W1f, 64, 64, (b - NB_BUILD) * 256 + tid);
    } else if (b < NB_BUILD + NB_P1 + NB_P2) {
        pack_w2_body(W2_rel, W2_root, W2f, 128, (b - NB_BUILD - NB_P1) * 256 + tid);
    } else if (b < NB_BUILD + NB_P1 + NB_P2 + NB_P3) {
        pack_w1_body(W3_rel, W3_root, W3f, 128, 128, (b - NB_BUILD - NB_P1 - NB_P2) * 256 + tid);
    } else {
        pack_w2_body(W4_rel, W4_root, W4f, 64, (b - NB_BUILD - NB_P1 - NB_P2 - NB_P3) * 256 + tid);
    }
}

// ---------------------------------------------------------------------------
// Per-graph fused gather+relu+mean-pool (one block = one graph; batch sorted).
// 256 threads = 16 node-slots x 16 col-groups (r14 A/B: 512 threads was
// neutral-to-negative; this is the r13 best-measured config).
// Pool partials reduced in LDS (r6 lesson: NO cross-XCD f32 atomics).
// ---------------------------------------------------------------------------
__global__ void gather_relu_pool(const bf16_t* __restrict__ y2, const bf16_t* __restrict__ init,
                                 const int* __restrict__ cnt, const int* __restrict__ bkt,
                                 const int* __restrict__ batch,
                                 bf16_t* __restrict__ h2, float* __restrict__ enc, int Nn) {
    int g = blockIdx.x;
    __shared__ int s_lo, s_hi;
    __shared__ float red[16][128];   // 8KB partials
    if (threadIdx.x == 0) {
        int lo = 0, hi = Nn;
        while (lo < hi) { int mid = (lo + hi) >> 1; if (batch[mid] < g) lo = mid + 1; else hi = mid; }
        s_lo = lo;
        hi = Nn;
        while (lo < hi) { int mid = (lo + hi) >> 1; if (batch[mid] < g + 1) lo = mid + 1; else hi = mid; }
        s_hi = lo;
    }
    __syncthreads();
    const int lo = s_lo, hi = s_hi;
    const int slot = threadIdx.x >> 4;      // 0..15 node slot
    const int j = (threadIdx.x & 15) * 8;   // col group
    float psum[8] = {0.f,0.f,0.f,0.f,0.f,0.f,0.f,0.f};
    for (int n = lo + slot; n < hi; n += 16) {
        int c = cnt[n]; if (c > BCAP) c = BCAP;
        const int* bp = bkt + n * BCAP;
        U4 u; u.v = *(const uint4*)(init + (size_t)n * 128 + j);
        float s[8];
        #pragma unroll
        for (int k = 0; k < 8; ++k) s[k] = us2f(u.s[k]);
        int i = 0;
        for (; i + 4 <= c; i += 4) {
            int s0 = bp[i], s1 = bp[i + 1], s2 = bp[i + 2], s3 = bp[i + 3];
            U4 w0, w1, w2, w3;
            w0.v = *(const uint4*)(y2 + (size_t)s0 * 128 + j);
            w1.v = *(const uint4*)(y2 + (size_t)s1 * 128 + j);
            w2.v = *(const uint4*)(y2 + (size_t)s2 * 128 + j);
            w3.v = *(const uint4*)(y2 + (size_t)s3 * 128 + j);
            #pragma unroll
            for (int k = 0; k < 8; ++k)
                s[k] += (us2f(w0.s[k]) + us2f(w1.s[k])) + (us2f(w2.s[k]) + us2f(w3.s[k]));
        }
        for (; i < c; ++i) {
            U4 w; w.v = *(const uint4*)(y2 + (size_t)bp[i] * 128 + j);
            #pragma unroll
            for (int k = 0; k < 8; ++k) s[k] += us2f(w.s[k]);
        }
        alignas(16) bf16_t ob[8];
        #pragma unroll
        for (int k = 0; k < 8; ++k) {
            s[k] = fmaxf(s[k], 0.f);
            psum[k] += s[k];
            ob[k] = f2b(s[k]);
        }
        *(uint4*)(h2 + (size_t)n * 128 + j) = *(const uint4*)ob;
    }
    #pragma unroll
    for (int k = 0; k < 8; ++k) red[slot][j + k] = psum[k];
    __syncthreads();
    if (threadIdx.x < 128) {
        int c = threadIdx.x;
        float tot = 0.f;
        #pragma unroll
        for (int r = 0; r < 16; ++r) tot += red[r][c];
        float n = (float)((hi - lo) > 0 ? (hi - lo) : 1);
        enc[(size_t)g * 128 + c] = tot / n;
    }
}

// outF[n] += sum nbr y4   (y4 bf16 [N,64]; outF f32 in-place on d_out)
__global__ void gather_add_b16_64(const bf16_t* __restrict__ y4, const int* __restrict__ cnt,
                                  const int* __restrict__ bkt, float* __restrict__ outF) {
    int t = blockIdx.x * 256 + threadIdx.x;
    int n = t >> 4;
    if (n >= NN) return;
    int j = (t & 15) * 4;
    int c = cnt[n]; if (c > BCAP) c = BCAP;
    const int* bp = bkt + n * BCAP;
    float4 sum = *(const float4*)(outF + n * 64 + j);
    int i = 0;
    for (; i + 4 <= c; i += 4) {
        int s0 = bp[i], s1 = bp[i + 1], s2 = bp[i + 2], s3 = bp[i + 3];
        U2 w0, w1, w2, w3;
        w0.v = *(const uint2*)(y4 + (size_t)s0 * 64 + j);
        w1.v = *(const uint2*)(y4 + (size_t)s1 * 64 + j);
        w2.v = *(const uint2*)(y4 + (size_t)s2 * 64 + j);
        w3.v = *(const uint2*)(y4 + (size_t)s3 * 64 + j);
        sum.x += (us2f(w0.s[0]) + us2f(w1.s[0])) + (us2f(w2.s[0]) + us2f(w3.s[0]));
        sum.y += (us2f(w0.s[1]) + us2f(w1.s[1])) + (us2f(w2.s[1]) + us2f(w3.s[1]));
        sum.z += (us2f(w0.s[2]) + us2f(w1.s[2])) + (us2f(w2.s[2]) + us2f(w3.s[2]));
        sum.w += (us2f(w0.s[3]) + us2f(w1.s[3])) + (us2f(w2.s[3]) + us2f(w3.s[3]));
    }
    for (; i < c; ++i) {
        U2 w; w.v = *(const uint2*)(y4 + (size_t)bp[i] * 64 + j);
        sum.x += us2f(w.s[0]); sum.y += us2f(w.s[1]);
        sum.z += us2f(w.s[2]); sum.w += us2f(w.s[3]);
    }
    *(float4*)(outF + n * 64 + j) = sum;
}

// ---------------------------------------------------------------------------
// Fused gather + two-GEMM v18 (r13 best measured config):
//   K=128 (fused1, NOUT=256): PD=4 cross-phase w1 prefetch (16 VGPRs live
//     across barriers, cheap) + 8-deep stage-2 with W2 dedup.
//   K=256 (fused2, NOUT=128): v16 path — 8-deep batches, no cross-phase
//     prefetch (PD=8 prefetch regressed: 32 VGPRs live across H-write).
//   Block = 64 nodes (2 node-tiles of 32), 512 threads = 8 waves.
// Outputs: outcol < NOUT/2 -> yout (bf16 if YBF16), else initout (+bias2).
// ---------------------------------------------------------------------------
template <int K, int NOUT, int F32OUT, int YBF16, int SRCF32>
__global__ __launch_bounds__(512, 4) void fused18(
    const void* __restrict__ src, const int* __restrict__ cnt,
    const int* __restrict__ bkt,
    const bf16_t* __restrict__ W1f, const float* __restrict__ bias1,
    const bf16_t* __restrict__ W2f, const float* __restrict__ bias2,
    void* __restrict__ yout, void* __restrict__ initout)
{
    constexpr int KT16 = K / 16;      // A k-tiles (16-deep): 8 or 16
    constexpr bool PREF = (K == 128); // cross-phase prefetch only when PD=4
    constexpr int PD   = KT16 / 2;    // w1 batch depth (4 or 8); 2 rounds
    constexpr int OT32 = NOUT / 32;   // out 32-col tiles (8 or 4)
    constexpr int OCT2 = OT32 / 4;    // out tiles per wave, old mapping (2 or 1)
    constexpr int NACC = (NOUT == 256) ? 2 : OCT2;
    constexpr int OH   = NOUT / 2;
    constexpr int SW   = K / 2;       // source row width (64 f32 / 128 bf16)
    constexpr int HALF = K / 16;      // 8-col groups per half (8 or 16)
    constexpr int STR  = F32OUT ? (NOUT + 4) : (NOUT + 8);
    __shared__ float b1sl[1024];
    __shared__ float b2sl[128];
    __shared__ __align__(16) char smem[(size_t)64 * K * 2 + 64 * 256 * 2];
    bf16_t* Asl = (bf16_t*)smem;                        // frag-major A tile [64*K]
    bf16_t* Hsl = (bf16_t*)(smem + (size_t)64 * K * 2); // frag-major H chunk [64*256]

    const int tid  = threadIdx.x;
    const int lane = tid & 63;
    const int wn   = tid >> 6;        // 0..7
    const int l31  = lane & 31;
    const int hi   = lane >> 5;
    const int og   = wn >> 1;         // old stage-2 out-col group
    const int wr   = wn & 1;          // old stage-2 node-tile
    const int bm0  = blockIdx.x * 64;

    for (int i = tid; i < 1024; i += 512) b1sl[i] = (i < 1000) ? bias1[i] : 0.f;
    if (tid < OH) b2sl[tid] = bias2[tid];

    // ---- prologue: gather + own-copy directly into Asl (frag-major)
    #pragma unroll
    for (int it = 0; it < (2 * 64 * HALF) / 512; ++it) {
        int task = it * 512 + tid;
        const bool own = task >= 64 * HALF;
        int t2 = own ? task - 64 * HALF : task;
        int i = t2 / HALF, s = t2 - (t2 / HALF) * HALF;
        int n = bm0 + i;
        int j = s * 8;
        float sum[8] = {0.f, 0.f, 0.f, 0.f, 0.f, 0.f, 0.f, 0.f};
        if (n < NN) {
            if (!own) {
                int c = cnt[n]; if (c > BCAP) c = BCAP;
                const int* bp = bkt + n * BCAP;
                int e = 0;
                for (; e + 4 <= c; e += 4) {
                    int s0 = bp[e], s1 = bp[e + 1], s2 = bp[e + 2], s3 = bp[e + 3];
                    if (SRCF32) {
                        const float* r0 = (const float*)src + (size_t)s0 * SW + j;
                        const float* r1 = (const float*)src + (size_t)s1 * SW + j;
                        const float* r2 = (const float*)src + (size_t)s2 * SW + j;
                        const float* r3 = (const float*)src + (size_t)s3 * SW + j;
                        float4 a0 = *(const float4*)r0, b0 = *(const float4*)(r0 + 4);
                        float4 a1 = *(const float4*)r1, b1 = *(const float4*)(r1 + 4);
                        float4 a2 = *(const float4*)r2, b2 = *(const float4*)(r2 + 4);
                        float4 a3 = *(const float4*)r3, b3 = *(const float4*)(r3 + 4);
                        sum[0] += (a0.x + a1.x) + (a2.x + a3.x);
                        sum[1] += (a0.y + a1.y) + (a2.y + a3.y);
                        sum[2] += (a0.z + a1.z) + (a2.z + a3.z);
                        sum[3] += (a0.w + a1.w) + (a2.w + a3.w);
                        sum[4] += (b0.x + b1.x) + (b2.x + b3.x);
                        sum[5] += (b0.y + b1.y) + (b2.y + b3.y);
                        sum[6] += (b0.z + b1.z) + (b2.z + b3.z);
                        sum[7] += (b0.w + b1.w) + (b2.w + b3.w);
                    } else {
                        U4 w0, w1, w2, w3;
                        w0.v = *(const uint4*)((const bf16_t*)src + (size_t)s0 * SW + j);
                        w1.v = *(const uint4*)((const bf16_t*)src + (size_t)s1 * SW + j);
                        w2.v = *(const uint4*)((const bf16_t*)src + (size_t)s2 * SW + j);
                        w3.v = *(const uint4*)((const bf16_t*)src + (size_t)s3 * SW + j);
                        #pragma unroll
                        for (int k = 0; k < 8; ++k)
                            sum[k] += (us2f(w0.s[k]) + us2f(w1.s[k])) + (us2f(w2.s[k]) + us2f(w3.s[k]));
                    }
                }
                for (; e < c; ++e) {
                    int sn = bp[e];
                    if (SRCF32) {
                        const float* r = (const float*)src + (size_t)sn * SW + j;
                        float4 a = *(const float4*)r;
                        float4 b = *(const float4*)(r + 4);
                        sum[0] += a.x; sum[1] += a.y; sum[2] += a.z; sum[3] += a.w;
                        sum[4] += b.x; sum[5] += b.y; sum[6] += b.z; sum[7] += b.w;
                    } else {
                        U4 w; w.v = *(const uint4*)((const bf16_t*)src + (size_t)sn * SW + j);
                        #pragma unroll
                        for (int k = 0; k < 8; ++k) sum[k] += us2f(w.s[k]);
                    }
                }
            } else {
                if (SRCF32) {
                    const float* r = (const float*)src + (size_t)n * SW + j;
                    float4 a = *(const float4*)r;
                    float4 b = *(const float4*)(r + 4);
                    sum[0] = a.x; sum[1] = a.y; sum[2] = a.z; sum[3] = a.w;
                    sum[4] = b.x; sum[5] = b.y; sum[6] = b.z; sum[7] = b.w;
                } else {
                    U4 w; w.v = *(const uint4*)((const bf16_t*)src + (size_t)n * SW + j);
                    #pragma unroll
                    for (int k = 0; k < 8; ++k) sum[k] = us2f(w.s[k]);
                }
            }
        }
        int cc = (own ? K / 2 : 0) + j;           // column in A's K-space
        int off = (((i >> 5) * KT16 + (cc >> 4)) * 64 + ((cc >> 3) & 1) * 32 + (i & 31)) * 8;
        alignas(16) bf16_t ob[8];
        #pragma unroll
        for (int k = 0; k < 8; ++k) ob[k] = f2b(sum[k]);
        *(uint4*)(&Asl[off]) = *(const uint4*)ob;
    }

    floatx16 acc2[NACC];
    #pragma unroll
    for (int oo = 0; oo < NACC; ++oo) acc2[oo] = (floatx16)FZ16;

    // (PREF only) prefetch chunk-0's first w1 batch BEFORE the barrier
    short8 w1pre[PD];
    if (PREF) {
        const bf16_t* w1p0 = W1f + (((size_t)(0 * 8 + wn) * KT16) * 64 + lane) * 8;
        #pragma unroll
        for (int u = 0; u < PD; ++u)
            w1pre[u] = *(const short8*)(w1p0 + (size_t)u * 512);
    }

    barrier_lds();   // Asl + biases ready

    for (int ci = 0; ci < 4; ++ci) {
        // ---- stage 1
        floatx16 acc1[2];
        acc1[0] = (floatx16)FZ16;
        acc1[1] = (floatx16)FZ16;

        const bf16_t* w1p = W1f + (((size_t)(ci * 8 + wn) * KT16) * 64 + lane) * 8;
        if (PREF) {
            // batch 0 from w1pre (in flight across barrier)
            __builtin_amdgcn_s_setprio(1);
            #pragma unroll
            for (int u = 0; u < PD; ++u) {
                short8 av0 = *(const short8*)&Asl[((0 * KT16 + u) * 64 + lane) * 8];
                acc1[0] = __builtin_amdgcn_mfma_f32_32x32x16_bf16(w1pre[u], av0, acc1[0], 0, 0, 0);
                short8 av1 = *(const short8*)&Asl[((1 * KT16 + u) * 64 + lane) * 8];
                acc1[1] = __builtin_amdgcn_mfma_f32_32x32x16_bf16(w1pre[u], av1, acc1[1], 0, 0, 0);
            }
            __builtin_amdgcn_s_setprio(0);
            short8 w1v[PD];
            #pragma unroll
            for (int u = 0; u < PD; ++u)
                w1v[u] = *(const short8*)(w1p + (size_t)(PD + u) * 512);
            __builtin_amdgcn_s_setprio(1);
            #pragma unroll
            for (int u = 0; u < PD; ++u) {
                int kk = PD + u;
                short8 av0 = *(const short8*)&Asl[((0 * KT16 + kk) * 64 + lane) * 8];
                acc1[0] = __builtin_amdgcn_mfma_f32_32x32x16_bf16(w1v[u], av0, acc1[0], 0, 0, 0);
                short8 av1 = *(const short8*)&Asl[((1 * KT16 + kk) * 64 + lane) * 8];
                acc1[1] = __builtin_amdgcn_mfma_f32_32x32x16_bf16(w1v[u], av1, acc1[1], 0, 0, 0);
            }
            __builtin_amdgcn_s_setprio(0);
        } else {
            // 8-deep batches, 2 rounds, no cross-phase prefetch
            #pragma unroll 1
            for (int kh = 0; kh < KT16 / 8; ++kh) {
                short8 w1v[8];
                #pragma unroll
                for (int u = 0; u < 8; ++u)
                    w1v[u] = *(const short8*)(w1p + (size_t)(kh * 8 + u) * 512);
                __builtin_amdgcn_s_setprio(1);
                #pragma unroll
                for (int u = 0; u < 8; ++u) {
                    int kk = kh * 8 + u;
                    short8 av0 = *(const short8*)&Asl[((0 * KT16 + kk) * 64 + lane) * 8];
                    acc1[0] = __builtin_amdgcn_mfma_f32_32x32x16_bf16(w1v[u], av0, acc1[0], 0, 0, 0);
                    short8 av1 = *(const short8*)&Asl[((1 * KT16 + kk) * 64 + lane) * 8];
                    acc1[1] = __builtin_amdgcn_mfma_f32_32x32x16_bf16(w1v[u], av1, acc1[1], 0, 0, 0);
                }
                __builtin_amdgcn_s_setprio(0);
            }
        }

        barrier_lds();   // previous chunk's stage-2 readers done with Hsl

        // bias+relu -> frag-major H; C/D: node=l31, hcol32=(r&3)+8*(r>>2)+4*hi
        #pragma unroll
        for (int nt2 = 0; nt2 < 2; ++nt2) {
            #pragma unroll
            for (int g = 0; g < 4; ++g) {
                float4 bv = *(const float4*)&b1sl[ci * 256 + wn * 32 + 8 * g + 4 * hi];
                const float* bvp = (const float*)&bv;
                alignas(8) bf16_t hb[4];
                #pragma unroll
                for (int e = 0; e < 4; ++e)
                    hb[e] = f2b(fmaxf(acc1[nt2][4 * g + e] + bvp[e], 0.f));
                int off = ((nt2 * 16 + wn * 2 + (g >> 1)) * 64 + (g & 1) * 32 + l31) * 8 + 4 * hi;
                *(uint2*)&Hsl[off] = *(const uint2*)hb;
            }
        }

        barrier_lds();   // H chunk visible

        // ---- stage 2
        if (NOUT == 256) {
            // dedup mapping + cross-phase w1 prefetch (PD=4, cheap)
            const int cin = (ci < 3) ? ci + 1 : 0;
            const bf16_t* w1pn = W1f + (((size_t)(cin * 8 + wn) * KT16) * 64 + lane) * 8;
            const bf16_t* w2p = W2f + (((size_t)wn * 64 + ci * 16) * 64 + lane) * 8;
            short8 w2v[8];
            // round 0: ks 0..7
            #pragma unroll
            for (int u = 0; u < 8; ++u)
                w2v[u] = *(const short8*)(w2p + (size_t)u * 512);
            __builtin_amdgcn_s_setprio(1);
            #pragma unroll
            for (int u = 0; u < 8; ++u) {
                short8 hf0 = *(const short8*)&Hsl[((0 * 16 + u) * 64 + lane) * 8];
                acc2[0] = __builtin_amdgcn_mfma_f32_32x32x16_bf16(w2v[u], hf0, acc2[0], 0, 0, 0);
                short8 hf1 = *(const short8*)&Hsl[((1 * 16 + u) * 64 + lane) * 8];
                acc2[1] = __builtin_amdgcn_mfma_f32_32x32x16_bf16(w2v[u], hf1, acc2[1], 0, 0, 0);
            }
            __builtin_amdgcn_s_setprio(0);
            // round 1: ks 8..15 + w1 prefetch for cin
            #pragma unroll
            for (int u = 0; u < 8; ++u)
                w2v[u] = *(const short8*)(w2p + (size_t)(8 + u) * 512);
            #pragma unroll
            for (int u = 0; u < PD; ++u)
                w1pre[u] = *(const short8*)(w1pn + (size_t)u * 512);
            __builtin_amdgcn_s_setprio(1);
            #pragma unroll
            for (int u = 0; u < 8; ++u) {
                int ks = 8 + u;
                short8 hf0 = *(const short8*)&Hsl[((0 * 16 + ks) * 64 + lane) * 8];
                acc2[0] = __builtin_amdgcn_mfma_f32_32x32x16_bf16(w2v[u], hf0, acc2[0], 0, 0, 0);
                short8 hf1 = *(const short8*)&Hsl[((1 * 16 + ks) * 64 + lane) * 8];
                acc2[1] = __builtin_amdgcn_mfma_f32_32x32x16_bf16(w2v[u], hf1, acc2[1], 0, 0, 0);
            }
            __builtin_amdgcn_s_setprio(0);
        } else {
            // wave (og, wr): 1 out-tile x node-tile wr; 8-deep
            const bf16_t* w2p = W2f + ((((size_t)og) * 64 + ci * 16) * 64 + lane) * 8;
            #pragma unroll 1
            for (int kg = 0; kg < 2; ++kg) {
                short8 w2v[8];
                #pragma unroll
                for (int u = 0; u < 8; ++u)
                    w2v[u] = *(const short8*)(w2p + (size_t)(kg * 8 + u) * 512);
                __builtin_amdgcn_s_setprio(1);
                #pragma unroll
                for (int u = 0; u < 8; ++u) {
                    int ks = kg * 8 + u;
                    short8 hf = *(const short8*)&Hsl[((wr * 16 + ks) * 64 + lane) * 8];
                    acc2[0] = __builtin_amdgcn_mfma_f32_32x32x16_bf16(w2v[u], hf, acc2[0], 0, 0, 0);
                }
                __builtin_amdgcn_s_setprio(0);
            }
        }
    }

    // ---- epilogue: stage acc2(+bias) into LDS [node][outcol] (padded),
    //      then copy full rows out with coalesced line-aligned stores.
    barrier_lds();   // everyone done reading Hsl/Asl
    if (NOUT == 256) {
        bf16_t* st = (bf16_t*)smem;
        #pragma unroll
        for (int nt2 = 0; nt2 < 2; ++nt2) {
            const int r = nt2 * 32 + l31;
            #pragma unroll
            for (int g = 0; g < 4; ++g) {
                int oc = wn * 32 + 8 * g + 4 * hi;
                const bool isInit = (oc >= OH);
                int col = isInit ? oc - OH : oc;
                float4 bv = isInit ? *(const float4*)&b2sl[col]
                                   : make_float4(0.f, 0.f, 0.f, 0.f);
                const float* bvp = (const float*)&bv;
                alignas(8) bf16_t ob[4];
                #pragma unroll
                for (int e = 0; e < 4; ++e) ob[e] = f2b(acc2[nt2][4 * g + e] + bvp[e]);
                *(uint2*)&st[r * STR + oc] = *(const uint2*)ob;
            }
        }
    } else {
        const int r = wr * 32 + l31;   // node row within block
        float* st = (float*)smem;      // f32 staging (F32OUT=1 for NOUT=128)
        #pragma unroll
        for (int oo = 0; oo < OCT2; ++oo) {
            int o = og * OCT2 + oo;
            #pragma unroll
            for (int g = 0; g < 4; ++g) {
                int oc = o * 32 + 8 * g + 4 * hi;
                const bool isInit = (oc >= OH);
                int col = isInit ? oc - OH : oc;
                float4 bv = isInit ? *(const float4*)&b2sl[col]
                                   : make_float4(0.f, 0.f, 0.f, 0.f);
                const float* bvp = (const float*)&bv;
                float v[4];
                #pragma unroll
                for (int e = 0; e < 4; ++e) v[e] = acc2[oo][4 * g + e] + bvp[e];
                *(float4*)&st[r * STR + oc] = make_float4(v[0], v[1], v[2], v[3]);
            }
        }
    }
    barrier_lds();   // staging written
    if (NOUT == 256) {
        constexpr int CH = NOUT / 8;
        constexpr int CHH = CH / 2;
        const bf16_t* st = (const bf16_t*)smem;
        for (int t = tid; t < 64 * CH; t += 512) {
            int nd = t / CH, c = t - (t / CH) * CH;
            int node = bm0 + nd;
            if (node >= NN) continue;
            const bool isInit = (c >= CHH);
            int ch = isInit ? c - CHH : c;
            uint4 v = *(const uint4*)&st[nd * STR + c * 8];
            bf16_t* dst = isInit ? (bf16_t*)initout : (bf16_t*)yout;
            *(uint4*)(dst + (size_t)node * OH + ch * 8) = v;
        }
    } else {
        const float* st = (const float*)smem;
        for (int t = tid; t < 64 * (OH / 4); t += 512) {
            int nd = t / (OH / 4), c = t - (t / (OH / 4)) * (OH / 4);
            int node = bm0 + nd;
            if (node >= NN) continue;
            float4 v = *(const float4*)&st[nd * STR + OH + c * 4];
            *(float4*)((float*)initout + (size_t)node * OH + c * 4) = v;
        }
        if (YBF16) {
            for (int t = tid; t < 64 * (OH / 8); t += 512) {
                int nd = t / (OH / 8), c = t - (t / (OH / 8)) * (OH / 8);
                int node = bm0 + nd;
                if (node >= NN) continue;
                float4 a = *(const float4*)&st[nd * STR + c * 8];
                float4 b = *(const float4*)&st[nd * STR + c * 8 + 4];
                alignas(16) bf16_t ob[8];
                ob[0] = f2b(a.x); ob[1] = f2b(a.y); ob[2] = f2b(a.z); ob[3] = f2b(a.w);
                ob[4] = f2b(b.x); ob[5] = f2b(b.y); ob[6] = f2b(b.z); ob[7] = f2b(b.w);
                *(uint4*)((bf16_t*)yout + (size_t)node * OH + c * 8) = *(const uint4*)ob;
            }
        } else {
            for (int t = tid; t < 64 * (OH / 4); t += 512) {
                int nd = t / (OH / 4), c = t - (t / (OH / 4)) * (OH / 4);
                int node = bm0 + nd;
                if (node >= NN) continue;
                float4 v = *(const float4*)&st[nd * STR + c * 4];
                *(float4*)((float*)yout + (size_t)node * OH + c * 4) = v;
            }
        }
    }
}

// ---------------------------------------------------------------------------
// Launch
// ---------------------------------------------------------------------------
extern "C" void kernel_launch(void* const* d_in, const int* in_sizes, int n_in,
                              void* d_out, int out_size, void* d_ws, size_t ws_size,
                              hipStream_t stream) {
    const float* x       = (const float*)d_in[0];
    const int*   ei      = (const int*)d_in[1];
    const int*   batch   = (const int*)d_in[2];
    const float* W1_rel  = (const float*)d_in[3];
    const float* b1      = (const float*)d_in[4];
    const float* W1_root = (const float*)d_in[5];
    const float* W2_rel  = (const float*)d_in[6];
    const float* b2      = (const float*)d_in[7];
    const float* W2_root = (const float*)d_in[8];
    const float* W3_rel  = (const float*)d_in[9];
    const float* b3      = (const float*)d_in[10];
    const float* W3_root = (const float*)d_in[11];
    const float* W4_rel  = (const float*)d_in[12];
    const float* b4      = (const float*)d_in[13];
    const float* W4_root = (const float*)d_in[14];

    float* outF = (float*)d_out;            // [N,64] then [G,128]
    float* enc  = outF + NN * 64;

    char* ws = (char*)d_ws;                         // ~66 MB
    bf16_t* y2buf  = (bf16_t*)(ws + 0);             // [N,128] bf16
    bf16_t* h2init = (bf16_t*)(ws + 12800000ULL);   // [N,128] bf16
    bf16_t* h2buf  = (bf16_t*)(ws + 25600000ULL);   // [N,128] bf16
    bf16_t* y4buf  = (bf16_t*)(ws + 38400000ULL);   // [N,64] bf16
    int*    cnt    = (int*)(ws + 51200000ULL);      // [N]
    int*    bkt    = (int*)(ws + 51400064ULL);      // [N*64]
    bf16_t* W1f    = (bf16_t*)(ws + 64200064ULL);   // 1024x128 frag-major
    bf16_t* W2f    = (bf16_t*)(ws + 64462208ULL);   // 256x1024 frag-major
    bf16_t* W3f    = (bf16_t*)(ws + 64986496ULL);   // 1024x256 frag-major
    bf16_t* W4f    = (bf16_t*)(ws + 65510784ULL);   // 128x1024 frag-major

    const int RB64 = (NN + 63) / 64;  // 782

    // ---- adjacency + all weight packs in one launch
    hipMemsetAsync(cnt, 0, NN * sizeof(int), stream);
    setup_all<<<NB_BUILD + NB_P1 + NB_P2 + NB_P3 + NB_P4, 256, 0, stream>>>(
        ei, cnt, bkt, W1_rel, W1_root, W2_rel, W2_root,
        W3_rel, W3_root, W4_rel, W4_root, W1f, W2f, W3f, W4f);

    // ---- L1+L2 fused: A=[gather(x)|x]; h1 on-chip;
    //      y2 = h1@W2_rel^T (bf16), h2init = h1@W2_root^T + b2 (bf16)
    fused18<128, 256, 0, 0, 1><<<RB64, 512, 0, stream>>>(x, cnt, bkt, W1f, b1, W2f, b2, y2buf, h2init);

    // ---- h2 = relu(h2init + gather(y2)); encoded = mean-pool(h2), fused
    gather_relu_pool<<<GG, 256, 0, stream>>>(y2buf, h2init, cnt, bkt, batch, h2buf, enc, NN);

    // ---- L3+L4 fused: A=[gather(h2)|h2]; h3 on-chip;
    //      y4 = h3@W4_rel^T (bf16), outF = h3@W4_root^T + b4 (f32, direct)
    fused18<256, 128, 1, 1, 0><<<RB64, 512, 0, stream>>>(h2buf, cnt, bkt, W3f, b3, W4f, b4, y4buf, outF);

    // ---- out = outF + gather(y4)   (y4 bf16 halves neighbor-read traffic)
    gather_add_b16_64<<<(NN * 16 + 255) / 256, 256, 0, stream>>>(y4buf, cnt, bkt, outF);
}